// Round 2
// baseline (1641.873 us; speedup 1.0000x reference)
//
#include <hip/hip_runtime.h>
#include <math.h>

#define N_NODES 100000
#define N_EDGES 1600000
#define D_FEAT 64
#define EPS 1e-7f

// ---- order-preserving float<->uint encoding for atomicMax on floats ----
__device__ __forceinline__ unsigned enc_f32(float f) {
    unsigned u = __float_as_uint(f);
    return (u & 0x80000000u) ? ~u : (u | 0x80000000u);
}
__device__ __forceinline__ float dec_f32(unsigned u) {
    u = (u & 0x80000000u) ? (u & 0x7FFFFFFFu) : ~u;
    return __uint_as_float(u);
}

// Zero out[] (as float4) plus encmax[]/segsum[].
__global__ void init_kernel(float4* __restrict__ out4, unsigned* __restrict__ encmax,
                            float* __restrict__ segsum, int total4) {
    int i = blockIdx.x * blockDim.x + threadIdx.x;
    if (i < total4) out4[i] = make_float4(0.f, 0.f, 0.f, 0.f);
    if (i < N_NODES) { encmax[i] = 0u; segsum[i] = 0.0f; }
}

// 16 lanes per node, float4 loads: nrm[i] = ||x[i]||
__global__ void norm_kernel(const float4* __restrict__ x4, float* __restrict__ nrm) {
    int tid = blockIdx.x * blockDim.x + threadIdx.x;
    int node = tid >> 4;
    int lane = tid & 15;
    if (node >= N_NODES) return;
    float4 v = x4[(size_t)node * 16 + lane];
    float s = v.x * v.x + v.y * v.y + v.z * v.z + v.w * v.w;
    s += __shfl_xor(s, 1);
    s += __shfl_xor(s, 2);
    s += __shfl_xor(s, 4);
    s += __shfl_xor(s, 8);
    if (lane == 0) nrm[node] = sqrtf(s);
}

// 16 lanes per edge, float4 gathers: sim = beta * cos(x[row], x[col]);
// segment max by row via encoded atomicMax.
__global__ void sim_kernel(const float4* __restrict__ x4, const int* __restrict__ row,
                           const int* __restrict__ col, const float* __restrict__ beta_p,
                           const float* __restrict__ nrm, float* __restrict__ sim,
                           unsigned* __restrict__ encmax) {
    int tid = blockIdx.x * blockDim.x + threadIdx.x;
    int e = tid >> 4;
    int lane = tid & 15;
    if (e >= N_EDGES) return;
    int r = row[e], c = col[e];
    float4 a = x4[(size_t)r * 16 + lane];
    float4 b = x4[(size_t)c * 16 + lane];
    float s = a.x * b.x + a.y * b.y + a.z * b.z + a.w * b.w;
    s += __shfl_xor(s, 1);
    s += __shfl_xor(s, 2);
    s += __shfl_xor(s, 4);
    s += __shfl_xor(s, 8);
    if (lane == 0) {
        float denom = nrm[r] * nrm[c] + EPS;
        float sv = beta_p[0] * (s / denom);
        sim[e] = sv;
        atomicMax(&encmax[r], enc_f32(sv));
    }
}

// One thread per edge: e = exp(sim - segmax[row]); segsum[row] += e; sim <- e
__global__ void expsum_kernel(const int* __restrict__ row, float* __restrict__ sim,
                              const unsigned* __restrict__ encmax,
                              float* __restrict__ segsum) {
    int e = blockIdx.x * blockDim.x + threadIdx.x;
    if (e >= N_EDGES) return;
    int r = row[e];
    float m = dec_f32(encmax[r]);
    float ex = expf(sim[e] - m);
    sim[e] = ex;
    atomicAdd(&segsum[r], ex);
}

// 16 lanes per edge: P = e/segsum[row]; out[col] += x[row] * P (4 atomics/lane)
__global__ void scatter_kernel(const float4* __restrict__ x4, const int* __restrict__ row,
                               const int* __restrict__ col, const float* __restrict__ sim,
                               const float* __restrict__ segsum, float* __restrict__ out) {
    int tid = blockIdx.x * blockDim.x + threadIdx.x;
    int e = tid >> 4;
    int lane = tid & 15;
    if (e >= N_EDGES) return;
    int r = row[e], c = col[e];
    float P = sim[e] / segsum[r];
    float4 a = x4[(size_t)r * 16 + lane];
    float* o = out + (size_t)c * D_FEAT + lane * 4;
    atomicAdd(o + 0, a.x * P);
    atomicAdd(o + 1, a.y * P);
    atomicAdd(o + 2, a.z * P);
    atomicAdd(o + 3, a.w * P);
}

extern "C" void kernel_launch(void* const* d_in, const int* in_sizes, int n_in,
                              void* d_out, int out_size, void* d_ws, size_t ws_size,
                              hipStream_t stream) {
    const float* x      = (const float*)d_in[0];
    const int*   row    = (const int*)d_in[1];
    const int*   col    = (const int*)d_in[2];
    const float* beta_p = (const float*)d_in[3];
    float* out = (float*)d_out;
    const float4* x4 = (const float4*)x;

    // workspace layout
    char* ws = (char*)d_ws;
    float*    sim    = (float*)ws;                                   // E floats
    unsigned* encmax = (unsigned*)(ws + (size_t)N_EDGES * 4);        // N u32
    float*    segsum = (float*)(ws + (size_t)N_EDGES * 4 + (size_t)N_NODES * 4);
    float*    nrm    = (float*)(ws + (size_t)N_EDGES * 4 + (size_t)N_NODES * 8);

    const int B = 256;

    int total4 = out_size / 4;                       // out_size = N_NODES*64
    int init_grid = (total4 + B - 1) / B;
    init_kernel<<<init_grid, B, 0, stream>>>((float4*)out, encmax, segsum, total4);

    int norm_threads = N_NODES * 16;
    norm_kernel<<<(norm_threads + B - 1) / B, B, 0, stream>>>(x4, nrm);

    long edge_threads = (long)N_EDGES * 16;
    int edge_grid = (int)((edge_threads + B - 1) / B);
    sim_kernel<<<edge_grid, B, 0, stream>>>(x4, row, col, beta_p, nrm, sim, encmax);

    int exp_grid = (N_EDGES + B - 1) / B;
    expsum_kernel<<<exp_grid, B, 0, stream>>>(row, sim, encmax, segsum);

    scatter_kernel<<<edge_grid, B, 0, stream>>>(x4, row, col, sim, segsum, out);
}

// Round 3
// 409.318 us; speedup vs baseline: 4.0112x; 4.0112x over previous
//
#include <hip/hip_runtime.h>
#include <math.h>

#define N_NODES 100000
#define N_EDGES 1600000
#define D_FEAT 64
#define EPS 1e-7f

__device__ __forceinline__ float4 f4fma(float4 acc, float p, float4 a) {
    acc.x += p * a.x; acc.y += p * a.y; acc.z += p * a.z; acc.w += p * a.w;
    return acc;
}

// Zero segsum[N] and cnt[N] (+1 pad).
__global__ void init_kernel(float* __restrict__ segsum, unsigned* __restrict__ cnt) {
    int i = blockIdx.x * blockDim.x + threadIdx.x;
    if (i <= N_NODES) { cnt[i] = 0u; if (i < N_NODES) segsum[i] = 0.0f; }
}

// 16 lanes per node, float4 loads: nrm[i] = ||x[i]||
__global__ void norm_kernel(const float4* __restrict__ x4, float* __restrict__ nrm) {
    int tid = blockIdx.x * blockDim.x + threadIdx.x;
    int node = tid >> 4;
    int lane = tid & 15;
    if (node >= N_NODES) return;
    float4 v = x4[(size_t)node * 16 + lane];
    float s = v.x * v.x + v.y * v.y + v.z * v.z + v.w * v.w;
    s += __shfl_xor(s, 1);
    s += __shfl_xor(s, 2);
    s += __shfl_xor(s, 4);
    s += __shfl_xor(s, 8);
    if (lane == 0) nrm[node] = sqrtf(s);
}

// 16 lanes per edge: ex = exp(beta*cos(x[row],x[col])) (no max-sub needed:
// |beta*cos| < 1 so exp is in (0.37, 2.72)). Accumulate segsum[row], hist cnt[col].
__global__ void sim_kernel(const float4* __restrict__ x4, const int* __restrict__ row,
                           const int* __restrict__ col, const float* __restrict__ beta_p,
                           const float* __restrict__ nrm, float* __restrict__ exsim,
                           float* __restrict__ segsum, unsigned* __restrict__ cnt) {
    int tid = blockIdx.x * blockDim.x + threadIdx.x;
    int e = tid >> 4;
    int lane = tid & 15;
    if (e >= N_EDGES) return;
    int r = row[e], c = col[e];
    float4 a = x4[(size_t)r * 16 + lane];
    float4 b = x4[(size_t)c * 16 + lane];
    float s = a.x * b.x + a.y * b.y + a.z * b.z + a.w * b.w;
    s += __shfl_xor(s, 1);
    s += __shfl_xor(s, 2);
    s += __shfl_xor(s, 4);
    s += __shfl_xor(s, 8);
    if (lane == 0) {
        float denom = nrm[r] * nrm[c] + EPS;
        float ex = expf(beta_p[0] * (s / denom));
        exsim[e] = ex;
        atomicAdd(&segsum[r], ex);
        atomicAdd(&cnt[c], 1u);
    }
}

// ---- hierarchical exclusive scan over cnt[0..N) -> offs, cursor ----
#define SCAN_B 256
__global__ void scan1_kernel(const unsigned* __restrict__ cnt, unsigned* __restrict__ incl,
                             unsigned* __restrict__ bsum) {
    __shared__ unsigned sh[SCAN_B];
    int i = blockIdx.x * SCAN_B + threadIdx.x;
    unsigned v = (i < N_NODES) ? cnt[i] : 0u;
    sh[threadIdx.x] = v;
    __syncthreads();
    for (int off = 1; off < SCAN_B; off <<= 1) {
        unsigned u = (threadIdx.x >= off) ? sh[threadIdx.x - off] : 0u;
        __syncthreads();
        sh[threadIdx.x] += u;
        __syncthreads();
    }
    if (i < N_NODES) incl[i] = sh[threadIdx.x];
    if (threadIdx.x == SCAN_B - 1) bsum[blockIdx.x] = sh[SCAN_B - 1];
}

// single block: exclusive-scan bsum[0..nblocks)
__global__ void scan2_kernel(unsigned* __restrict__ bsum, int nblocks) {
    __shared__ unsigned sh[512];
    int t = threadIdx.x;
    unsigned v = (t < nblocks) ? bsum[t] : 0u;
    sh[t] = v;
    __syncthreads();
    for (int off = 1; off < 512; off <<= 1) {
        unsigned u = (t >= off) ? sh[t - off] : 0u;
        __syncthreads();
        sh[t] += u;
        __syncthreads();
    }
    if (t < nblocks) bsum[t] = sh[t] - v;  // exclusive
}

// offs[i] = bsum[blk] + incl[i] - cnt[i] (exclusive start); cursor[i] = same; offs[N]=E
__global__ void scan3_kernel(const unsigned* __restrict__ cnt, const unsigned* __restrict__ incl,
                             const unsigned* __restrict__ bsum, unsigned* __restrict__ offs,
                             unsigned* __restrict__ cursor) {
    int i = blockIdx.x * SCAN_B + threadIdx.x;
    if (i < N_NODES) {
        unsigned o = bsum[blockIdx.x] + incl[i] - cnt[i];
        offs[i] = o;
        cursor[i] = o;
    } else if (i == N_NODES) {
        offs[N_NODES] = N_EDGES;
    }
}

// One thread per edge: bin (row, P) payload into col-sorted arrays.
__global__ void place_kernel(const int* __restrict__ row, const int* __restrict__ col,
                             const float* __restrict__ exsim, const float* __restrict__ segsum,
                             unsigned* __restrict__ cursor, unsigned* __restrict__ srow,
                             float* __restrict__ sp) {
    int e = blockIdx.x * blockDim.x + threadIdx.x;
    if (e >= N_EDGES) return;
    int r = row[e], c = col[e];
    float p = exsim[e] / segsum[r];
    unsigned pos = atomicAdd(&cursor[c], 1u);
    srow[pos] = (unsigned)r;
    sp[pos] = p;
}

// 16 lanes per node: out[n] = sum over incoming edges of P * x[row]; no atomics.
__global__ void gather_kernel(const float4* __restrict__ x4, const unsigned* __restrict__ offs,
                              const unsigned* __restrict__ srow, const float* __restrict__ sp,
                              float4* __restrict__ out4) {
    int tid = blockIdx.x * blockDim.x + threadIdx.x;
    int node = tid >> 4;
    int lane = tid & 15;
    if (node >= N_NODES) return;
    int start = (int)offs[node];
    int end = (int)offs[node + 1];
    float4 acc = make_float4(0.f, 0.f, 0.f, 0.f);
    int i = start;
    for (; i + 1 < end; i += 2) {
        unsigned r0 = srow[i], r1 = srow[i + 1];
        float p0 = sp[i], p1 = sp[i + 1];
        float4 a0 = x4[(size_t)r0 * 16 + lane];
        float4 a1 = x4[(size_t)r1 * 16 + lane];
        acc = f4fma(acc, p0, a0);
        acc = f4fma(acc, p1, a1);
    }
    if (i < end) {
        unsigned r0 = srow[i];
        float p0 = sp[i];
        acc = f4fma(acc, p0, x4[(size_t)r0 * 16 + lane]);
    }
    out4[(size_t)node * 16 + lane] = acc;
}

extern "C" void kernel_launch(void* const* d_in, const int* in_sizes, int n_in,
                              void* d_out, int out_size, void* d_ws, size_t ws_size,
                              hipStream_t stream) {
    const float* x      = (const float*)d_in[0];
    const int*   row    = (const int*)d_in[1];
    const int*   col    = (const int*)d_in[2];
    const float* beta_p = (const float*)d_in[3];
    const float4* x4 = (const float4*)x;
    float4* out4 = (float4*)d_out;

    // workspace layout (bytes)
    const size_t E4 = (size_t)N_EDGES * 4;       // 6,400,000
    const size_t S  = 400064;                    // padded N-array stride (16-aligned)
    char* ws = (char*)d_ws;
    float*    exsim  = (float*)ws;                       // E f32
    unsigned* srow   = (unsigned*)(ws + E4);             // E u32
    float*    sp     = (float*)(ws + 2 * E4);            // E f32
    char* base3 = ws + 3 * E4;
    float*    segsum = (float*)(base3 + 0 * S);          // N f32
    float*    nrm    = (float*)(base3 + 1 * S);          // N f32
    unsigned* cnt    = (unsigned*)(base3 + 2 * S);       // N+1 u32
    unsigned* incl   = (unsigned*)(base3 + 3 * S);       // N u32
    unsigned* offs   = (unsigned*)(base3 + 4 * S);       // N+1 u32
    unsigned* cursor = (unsigned*)(base3 + 5 * S);       // N u32
    unsigned* bsum   = (unsigned*)(base3 + 6 * S);       // scan block sums

    const int B = 256;
    const int nscan_blocks = (N_NODES + SCAN_B - 1) / SCAN_B;  // 391

    init_kernel<<<(N_NODES + 1 + B - 1) / B, B, 0, stream>>>(segsum, cnt);

    norm_kernel<<<(N_NODES * 16 + B - 1) / B, B, 0, stream>>>(x4, nrm);

    long edge_threads = (long)N_EDGES * 16;
    int edge_grid16 = (int)((edge_threads + B - 1) / B);
    sim_kernel<<<edge_grid16, B, 0, stream>>>(x4, row, col, beta_p, nrm, exsim, segsum, cnt);

    scan1_kernel<<<nscan_blocks, SCAN_B, 0, stream>>>(cnt, incl, bsum);
    scan2_kernel<<<1, 512, 0, stream>>>(bsum, nscan_blocks);
    scan3_kernel<<<nscan_blocks + 1, SCAN_B, 0, stream>>>(cnt, incl, bsum, offs, cursor);

    place_kernel<<<(N_EDGES + B - 1) / B, B, 0, stream>>>(row, col, exsim, segsum, cursor, srow, sp);

    gather_kernel<<<(N_NODES * 16 + B - 1) / B, B, 0, stream>>>(x4, offs, srow, sp, out4);
}

// Round 4
// 395.196 us; speedup vs baseline: 4.1546x; 1.0357x over previous
//
#include <hip/hip_runtime.h>
#include <math.h>

#define N_NODES 100000
#define N_EDGES 1600000
#define D_FEAT 64
#define EPS 1e-7f

__device__ __forceinline__ unsigned short f32_to_bf16_rtne(float f) {
    unsigned u = __float_as_uint(f);
    unsigned rounding = 0x7FFFu + ((u >> 16) & 1u);
    return (unsigned short)((u + rounding) >> 16);
}
__device__ __forceinline__ float bf16lo_to_f32(unsigned u) {   // low 16 bits
    return __uint_as_float(u << 16);
}
__device__ __forceinline__ float bf16hi_to_f32(unsigned u) {   // high 16 bits
    return __uint_as_float(u & 0xFFFF0000u);
}

__device__ __forceinline__ float4 f4fma(float4 acc, float p, float4 a) {
    acc.x += p * a.x; acc.y += p * a.y; acc.z += p * a.z; acc.w += p * a.w;
    return acc;
}

// Zero segsum[N] and cnt[N].
__global__ void init_kernel(float* __restrict__ segsum, unsigned* __restrict__ cnt) {
    int i = blockIdx.x * blockDim.x + threadIdx.x;
    if (i < N_NODES) { cnt[i] = 0u; segsum[i] = 0.0f; }
}

// 16 lanes per node: nrm[i] = ||x[i]|| AND xh[i] = bf16(x[i]) (packed 2/uint).
__global__ void norm_cvt_kernel(const float4* __restrict__ x4, float* __restrict__ nrm,
                                uint2* __restrict__ xh2) {
    int tid = blockIdx.x * blockDim.x + threadIdx.x;
    int node = tid >> 4;
    int lane = tid & 15;
    if (node >= N_NODES) return;
    float4 v = x4[(size_t)node * 16 + lane];
    // pack 4 floats -> 4 bf16 in uint2 (elem0 in low bits)
    uint2 h;
    h.x = (unsigned)f32_to_bf16_rtne(v.x) | ((unsigned)f32_to_bf16_rtne(v.y) << 16);
    h.y = (unsigned)f32_to_bf16_rtne(v.z) | ((unsigned)f32_to_bf16_rtne(v.w) << 16);
    xh2[(size_t)node * 16 + lane] = h;
    float s = v.x * v.x + v.y * v.y + v.z * v.z + v.w * v.w;
    s += __shfl_xor(s, 1);
    s += __shfl_xor(s, 2);
    s += __shfl_xor(s, 4);
    s += __shfl_xor(s, 8);
    if (lane == 0) nrm[node] = sqrtf(s);
}

// Histogram of col.
__global__ void hist_kernel(const int* __restrict__ col, unsigned* __restrict__ cnt) {
    int e = blockIdx.x * blockDim.x + threadIdx.x;
    if (e >= N_EDGES) return;
    atomicAdd(&cnt[col[e]], 1u);
}

// ---- hierarchical exclusive scan over cnt[0..N) -> offs, cursor ----
#define SCAN_B 256
__global__ void scan1_kernel(const unsigned* __restrict__ cnt, unsigned* __restrict__ incl,
                             unsigned* __restrict__ bsum) {
    __shared__ unsigned sh[SCAN_B];
    int i = blockIdx.x * SCAN_B + threadIdx.x;
    unsigned v = (i < N_NODES) ? cnt[i] : 0u;
    sh[threadIdx.x] = v;
    __syncthreads();
    for (int off = 1; off < SCAN_B; off <<= 1) {
        unsigned u = (threadIdx.x >= off) ? sh[threadIdx.x - off] : 0u;
        __syncthreads();
        sh[threadIdx.x] += u;
        __syncthreads();
    }
    if (i < N_NODES) incl[i] = sh[threadIdx.x];
    if (threadIdx.x == SCAN_B - 1) bsum[blockIdx.x] = sh[SCAN_B - 1];
}

__global__ void scan2_kernel(unsigned* __restrict__ bsum, int nblocks) {
    __shared__ unsigned sh[512];
    int t = threadIdx.x;
    unsigned v = (t < nblocks) ? bsum[t] : 0u;
    sh[t] = v;
    __syncthreads();
    for (int off = 1; off < 512; off <<= 1) {
        unsigned u = (t >= off) ? sh[t - off] : 0u;
        __syncthreads();
        sh[t] += u;
        __syncthreads();
    }
    if (t < nblocks) bsum[t] = sh[t] - v;  // exclusive
}

__global__ void scan3_kernel(const unsigned* __restrict__ cnt, const unsigned* __restrict__ incl,
                             const unsigned* __restrict__ bsum, unsigned* __restrict__ offs,
                             unsigned* __restrict__ cursor) {
    int i = blockIdx.x * SCAN_B + threadIdx.x;
    if (i < N_NODES) {
        unsigned o = bsum[blockIdx.x] + incl[i] - cnt[i];
        offs[i] = o;
        cursor[i] = o;
    } else if (i == N_NODES) {
        offs[N_NODES] = N_EDGES;
    }
}

// 8 lanes per edge, bf16 16B gathers: ex = exp(beta*cos(x[row],x[col]));
// segsum[row] += ex; write (row, ex) to col-sorted slot via cursor.
__global__ void simplace_kernel(const uint4* __restrict__ xh4, const int* __restrict__ row,
                                const int* __restrict__ col, const float* __restrict__ beta_p,
                                const float* __restrict__ nrm, float* __restrict__ segsum,
                                unsigned* __restrict__ cursor, unsigned* __restrict__ srow,
                                float* __restrict__ sex) {
    int tid = blockIdx.x * blockDim.x + threadIdx.x;
    int e = tid >> 3;
    int lane = tid & 7;
    if (e >= N_EDGES) return;
    int r = row[e], c = col[e];
    uint4 a = xh4[(size_t)r * 8 + lane];   // 8 bf16
    uint4 b = xh4[(size_t)c * 8 + lane];
    float s;
    s  = bf16lo_to_f32(a.x) * bf16lo_to_f32(b.x) + bf16hi_to_f32(a.x) * bf16hi_to_f32(b.x);
    s += bf16lo_to_f32(a.y) * bf16lo_to_f32(b.y) + bf16hi_to_f32(a.y) * bf16hi_to_f32(b.y);
    s += bf16lo_to_f32(a.z) * bf16lo_to_f32(b.z) + bf16hi_to_f32(a.z) * bf16hi_to_f32(b.z);
    s += bf16lo_to_f32(a.w) * bf16lo_to_f32(b.w) + bf16hi_to_f32(a.w) * bf16hi_to_f32(b.w);
    s += __shfl_xor(s, 1);
    s += __shfl_xor(s, 2);
    s += __shfl_xor(s, 4);
    if (lane == 0) {
        float denom = nrm[r] * nrm[c] + EPS;
        float ex = expf(beta_p[0] * (s / denom));
        atomicAdd(&segsum[r], ex);
        unsigned pos = atomicAdd(&cursor[c], 1u);
        srow[pos] = (unsigned)r;
        sex[pos] = ex;
    }
}

// 16 lanes per node: out[n] = sum over incoming edges of (ex/segsum[row]) * x[row].
__global__ void gather_kernel(const float4* __restrict__ x4, const unsigned* __restrict__ offs,
                              const unsigned* __restrict__ srow, const float* __restrict__ sex,
                              const float* __restrict__ segsum, float4* __restrict__ out4) {
    int tid = blockIdx.x * blockDim.x + threadIdx.x;
    int node = tid >> 4;
    int lane = tid & 15;
    if (node >= N_NODES) return;
    int start = (int)offs[node];
    int end = (int)offs[node + 1];
    float4 acc = make_float4(0.f, 0.f, 0.f, 0.f);
    int i = start;
    for (; i + 1 < end; i += 2) {
        unsigned r0 = srow[i], r1 = srow[i + 1];
        float p0 = sex[i] / segsum[r0];
        float p1 = sex[i + 1] / segsum[r1];
        float4 a0 = x4[(size_t)r0 * 16 + lane];
        float4 a1 = x4[(size_t)r1 * 16 + lane];
        acc = f4fma(acc, p0, a0);
        acc = f4fma(acc, p1, a1);
    }
    if (i < end) {
        unsigned r0 = srow[i];
        float p0 = sex[i] / segsum[r0];
        acc = f4fma(acc, p0, x4[(size_t)r0 * 16 + lane]);
    }
    out4[(size_t)node * 16 + lane] = acc;
}

extern "C" void kernel_launch(void* const* d_in, const int* in_sizes, int n_in,
                              void* d_out, int out_size, void* d_ws, size_t ws_size,
                              hipStream_t stream) {
    const float* x      = (const float*)d_in[0];
    const int*   row    = (const int*)d_in[1];
    const int*   col    = (const int*)d_in[2];
    const float* beta_p = (const float*)d_in[3];
    const float4* x4 = (const float4*)x;
    float4* out4 = (float4*)d_out;

    // xh (bf16 copy of x, 12.8 MB) lives in d_out scratch — it's dead by the
    // time gather_kernel overwrites d_out, and the harness re-poisons d_out
    // before every launch anyway.
    uint2* xh2 = (uint2*)d_out;
    const uint4* xh4 = (const uint4*)d_out;

    // workspace layout (bytes): 2*E4 + 7*S = 15.6 MB (proven safe <= r3's 22 MB)
    const size_t E4 = (size_t)N_EDGES * 4;       // 6,400,000
    const size_t S  = 400064;                    // padded N-array stride
    char* ws = (char*)d_ws;
    unsigned* srow   = (unsigned*)ws;                    // E u32
    float*    sex    = (float*)(ws + E4);                // E f32
    char* base2 = ws + 2 * E4;
    float*    segsum = (float*)(base2 + 0 * S);          // N f32
    float*    nrm    = (float*)(base2 + 1 * S);          // N f32
    unsigned* cnt    = (unsigned*)(base2 + 2 * S);       // N u32
    unsigned* incl   = (unsigned*)(base2 + 3 * S);       // N u32
    unsigned* offs   = (unsigned*)(base2 + 4 * S);       // N+1 u32
    unsigned* cursor = (unsigned*)(base2 + 5 * S);       // N u32
    unsigned* bsum   = (unsigned*)(base2 + 6 * S);       // scan block sums

    const int B = 256;
    const int nscan_blocks = (N_NODES + SCAN_B - 1) / SCAN_B;  // 391

    init_kernel<<<(N_NODES + B - 1) / B, B, 0, stream>>>(segsum, cnt);

    norm_cvt_kernel<<<(N_NODES * 16 + B - 1) / B, B, 0, stream>>>(x4, nrm, xh2);

    hist_kernel<<<(N_EDGES + B - 1) / B, B, 0, stream>>>(col, cnt);

    scan1_kernel<<<nscan_blocks, SCAN_B, 0, stream>>>(cnt, incl, bsum);
    scan2_kernel<<<1, 512, 0, stream>>>(bsum, nscan_blocks);
    scan3_kernel<<<nscan_blocks + 1, SCAN_B, 0, stream>>>(cnt, incl, bsum, offs, cursor);

    long ethreads = (long)N_EDGES * 8;
    simplace_kernel<<<(int)((ethreads + B - 1) / B), B, 0, stream>>>(
        xh4, row, col, beta_p, nrm, segsum, cursor, srow, sex);

    gather_kernel<<<(N_NODES * 16 + B - 1) / B, B, 0, stream>>>(x4, offs, srow, sex, segsum, out4);
}